// Round 1
// baseline (246.531 us; speedup 1.0000x reference)
//
#include <hip/hip_runtime.h>

#define WEIGHT 0.1f
#define THRESH 0.3f
#define MARGIN 0.1f

struct Accum {
    double total;
    unsigned long long count;
};

__global__ void tc_init_kernel(Accum* acc) {
    acc->total = 0.0;
    acc->count = 0ull;
}

__global__ __launch_bounds__(256) void tc_main_kernel(
        const float4* __restrict__ pred,
        const float*  __restrict__ times,
        Accum* __restrict__ acc,
        int n) {
    float local = 0.0f;
    unsigned int cnt = 0;

    int idx = blockIdx.x * blockDim.x + threadIdx.x;
    int stride = gridDim.x * blockDim.x;
    for (int i = idx; i < n; i += stride) {
        float4 p = pred[i];      // p.y = p4, p.z = p5, p.w = p6 (p.x unused)
        float  t = times[i];

        bool g4 = p.y > THRESH;
        bool g5 = p.z > THRESH;
        bool g6 = p.w > THRESH;
        bool m45  = g4 && g5;
        bool m56  = g5 && g6;
        bool m456 = m45 && g6;

        float term45 = fmaxf(MARGIN - (p.z * t - p.y * t), 0.0f);
        float term56 = fmaxf(MARGIN - (p.w * t - p.z * t), 0.0f);
        float d45 = fabsf(p.z - p.y);
        float d56 = fabsf(p.w - p.z);
        float torder = fmaxf(d45 - d56 + MARGIN, 0.0f);

        local += (m45  ? term45 : 0.0f)
               + (m56  ? term56 : 0.0f)
               + (m456 ? torder : 0.0f);
        cnt += (unsigned)m45 + (unsigned)m56 + (unsigned)m456;
    }

    // Wave-64 butterfly reduction (double to be safe across big partials)
    double dl = (double)local;
    for (int o = 32; o > 0; o >>= 1) {
        dl  += __shfl_down(dl, o, 64);
        cnt += __shfl_down(cnt, o, 64);
    }

    __shared__ double       s_tot[4];
    __shared__ unsigned int s_cnt[4];
    int wave = threadIdx.x >> 6;
    int lane = threadIdx.x & 63;
    if (lane == 0) { s_tot[wave] = dl; s_cnt[wave] = cnt; }
    __syncthreads();

    if (threadIdx.x == 0) {
        double bt = 0.0;
        unsigned int bc = 0;
        int nwaves = blockDim.x >> 6;
        for (int w = 0; w < nwaves; ++w) { bt += s_tot[w]; bc += s_cnt[w]; }
        atomicAdd(&acc->total, bt);
        atomicAdd(&acc->count, (unsigned long long)bc);
    }
}

__global__ void tc_finalize_kernel(const Accum* __restrict__ acc, float* __restrict__ out) {
    double total = acc->total;
    double count = (double)acc->count;
    double loss  = (count > 0.0) ? (total / fmax(count, 1.0)) : total;
    out[0] = (float)((double)WEIGHT * loss);
}

extern "C" void kernel_launch(void* const* d_in, const int* in_sizes, int n_in,
                              void* d_out, int out_size, void* d_ws, size_t ws_size,
                              hipStream_t stream) {
    const float4* pred  = (const float4*)d_in[0];   // (B,4) fp32 -> one float4/row
    const float*  times = (const float*)d_in[1];    // (B,1) fp32
    int n = in_sizes[1];                            // B = rows

    Accum* acc = (Accum*)d_ws;

    tc_init_kernel<<<1, 1, 0, stream>>>(acc);

    // 2048 blocks x 256 thr = 524288 threads = max resident on 256 CUs;
    // 16 rows/thread via grid-stride, fully coalesced float4 loads.
    tc_main_kernel<<<2048, 256, 0, stream>>>(pred, times, acc, n);

    tc_finalize_kernel<<<1, 1, 0, stream>>>(acc, (float*)d_out);
}

// Round 2
// 215.454 us; speedup vs baseline: 1.1442x; 1.1442x over previous
//
#include <hip/hip_runtime.h>

#define WEIGHT 0.1f
#define THRESH 0.3f
#define MARGIN 0.1f

#define NBLOCKS 2048
#define NTHREADS 256

// d_ws layout: [0 .. NBLOCKS) doubles  = per-block totals
//              then NBLOCKS uints      = per-block counts
// Every launch writes ALL slots (grid is fixed), so 0xAA poison is harmless.

__device__ __forceinline__ void row_terms(float4 p, float t,
                                          float& acc, unsigned int& cnt) {
    bool g4 = p.y > THRESH;
    bool g5 = p.z > THRESH;
    bool g6 = p.w > THRESH;
    bool m45  = g4 && g5;
    bool m56  = g5 && g6;
    bool m456 = m45 && g6;

    float term45 = fmaxf(MARGIN - (p.z * t - p.y * t), 0.0f);
    float term56 = fmaxf(MARGIN - (p.w * t - p.z * t), 0.0f);
    float d45 = fabsf(p.z - p.y);
    float d56 = fabsf(p.w - p.z);
    float torder = fmaxf(d45 - d56 + MARGIN, 0.0f);

    acc += (m45  ? term45 : 0.0f)
         + (m56  ? term56 : 0.0f)
         + (m456 ? torder : 0.0f);
    cnt += (unsigned)m45 + (unsigned)m56 + (unsigned)m456;
}

__global__ __launch_bounds__(NTHREADS) void tc_main_kernel(
        const float4* __restrict__ pred,
        const float*  __restrict__ times,
        double*       __restrict__ blk_tot,
        unsigned int* __restrict__ blk_cnt,
        int n) {
    float local = 0.0f;
    unsigned int cnt = 0;

    const int stride = gridDim.x * blockDim.x;
    int i = blockIdx.x * blockDim.x + threadIdx.x;

    // 4x unroll: 4 independent float4 + 4 float loads in flight per thread.
    for (; i + 3 * stride < n; i += 4 * stride) {
        float4 p0 = pred[i];
        float4 p1 = pred[i + stride];
        float4 p2 = pred[i + 2 * stride];
        float4 p3 = pred[i + 3 * stride];
        float t0 = times[i];
        float t1 = times[i + stride];
        float t2 = times[i + 2 * stride];
        float t3 = times[i + 3 * stride];
        row_terms(p0, t0, local, cnt);
        row_terms(p1, t1, local, cnt);
        row_terms(p2, t2, local, cnt);
        row_terms(p3, t3, local, cnt);
    }
    for (; i < n; i += stride) {
        row_terms(pred[i], times[i], local, cnt);
    }

    // Wave-64 butterfly reduction (promote to double for the tree)
    double dl = (double)local;
    for (int o = 32; o > 0; o >>= 1) {
        dl  += __shfl_down(dl, o, 64);
        cnt += __shfl_down(cnt, o, 64);
    }

    __shared__ double       s_tot[NTHREADS / 64];
    __shared__ unsigned int s_cnt[NTHREADS / 64];
    int wave = threadIdx.x >> 6;
    int lane = threadIdx.x & 63;
    if (lane == 0) { s_tot[wave] = dl; s_cnt[wave] = cnt; }
    __syncthreads();

    if (threadIdx.x == 0) {
        double bt = 0.0;
        unsigned int bc = 0;
        for (int w = 0; w < NTHREADS / 64; ++w) { bt += s_tot[w]; bc += s_cnt[w]; }
        blk_tot[blockIdx.x] = bt;     // distinct slot per block: no contention
        blk_cnt[blockIdx.x] = bc;
    }
}

__global__ __launch_bounds__(NTHREADS) void tc_finalize_kernel(
        const double*       __restrict__ blk_tot,
        const unsigned int* __restrict__ blk_cnt,
        float* __restrict__ out) {
    double dl = 0.0;
    unsigned long long cl = 0;
    for (int i = threadIdx.x; i < NBLOCKS; i += NTHREADS) {
        dl += blk_tot[i];
        cl += blk_cnt[i];
    }
    for (int o = 32; o > 0; o >>= 1) {
        dl += __shfl_down(dl, o, 64);
        cl += __shfl_down(cl, o, 64);
    }
    __shared__ double             s_tot[NTHREADS / 64];
    __shared__ unsigned long long s_cnt[NTHREADS / 64];
    int wave = threadIdx.x >> 6;
    int lane = threadIdx.x & 63;
    if (lane == 0) { s_tot[wave] = dl; s_cnt[wave] = cl; }
    __syncthreads();
    if (threadIdx.x == 0) {
        double total = 0.0;
        unsigned long long count = 0;
        for (int w = 0; w < NTHREADS / 64; ++w) { total += s_tot[w]; count += s_cnt[w]; }
        double c = (double)count;
        double loss = (c > 0.0) ? (total / fmax(c, 1.0)) : total;
        out[0] = (float)((double)WEIGHT * loss);
    }
}

extern "C" void kernel_launch(void* const* d_in, const int* in_sizes, int n_in,
                              void* d_out, int out_size, void* d_ws, size_t ws_size,
                              hipStream_t stream) {
    const float4* pred  = (const float4*)d_in[0];   // (B,4) fp32 -> one float4/row
    const float*  times = (const float*)d_in[1];    // (B,1) fp32
    int n = in_sizes[1];                            // B = rows

    double*       blk_tot = (double*)d_ws;
    unsigned int* blk_cnt = (unsigned int*)((char*)d_ws + NBLOCKS * sizeof(double));

    tc_main_kernel<<<NBLOCKS, NTHREADS, 0, stream>>>(pred, times, blk_tot, blk_cnt, n);
    tc_finalize_kernel<<<1, NTHREADS, 0, stream>>>(blk_tot, blk_cnt, (float*)d_out);
}